// Round 4
// baseline (11972.440 us; speedup 1.0000x reference)
//
#include <hip/hip_runtime.h>

#define BATCH 2048
#define TTOT 48
#define TOUT 47
#define SS 128
#define HH 256
#define VV 96
#define MB 8                  // batch rows per block
#define NBLK (BATCH / MB)     // 256 -> one block per CU
#define NTHR 512              // 8 waves
#define SROW 260              // fp32 LDS row stride (16B-aligned, breaks bank stride)

// All-fp32 LDS working set (~87 KB -> 1 block/CU, which is all we need at 256 blocks)
struct __align__(16) SMem {
    float htF[MB * SROW];     // attentional hidden ht (prev step)
    float c0F[MB * SROW];     // GRU0 state
    float c1F[MB * SROW];     // GRU1 state (= "out" after update)
    float cxF[MB * SROW];     // attention context
    float gI[MB * 768];       // gate pre-activations x-side   (also wc partial kh=0)
    float gH[MB * 768];       // gate pre-activations h-side   (also wc partial kh=1)
    float eS[MB * 132];       // energies -> unnormalized probs
    float red[128];           // softmax tree partials
    float rowM[MB];
    float rowS[MB];           // 1/sum
    int   ymS[MB];
};

__device__ __forceinline__ float dot4(const float4 a, const float4 b) {
    return a.x * b.x + a.y * b.y + a.z * b.z + a.w * b.w;
}

// One GRU GEMV phase: gI[m][i] = bih[i] (+ Wih[i][ym[m]] if GATHER) + sum_k x[m][k]*Wih[i][kOff+k]
//                     gH[m][i] = bhh[i] + sum_k h[m][k]*Whh[i][k]
template <bool GATHER>
__device__ __forceinline__ void gru_gemv(
    const float* __restrict__ Wih, const int ihStride, const int ihOff,
    const float* __restrict__ Whh,
    const float* __restrict__ bih, const float* __restrict__ bhh,
    const float* xS, const float* hS, const int* ymS,
    float* gI, float* gH, const int tid)
{
    for (int i = tid; i < 768; i += NTHR) {
        const float* wI = Wih + (size_t)i * ihStride + ihOff;
        const float* wH = Whh + (size_t)i * 256;
        float aI[MB], aH[MB];
        const float bi = bih[i], bh = bhh[i];
        #pragma unroll
        for (int m = 0; m < MB; ++m) {
            aI[m] = GATHER ? (bi + Wih[(size_t)i * ihStride + ymS[m]]) : bi;
            aH[m] = bh;
        }
        #pragma unroll 4
        for (int k = 0; k < 256; k += 4) {
            const float4 wi4 = *(const float4*)(wI + k);
            const float4 wh4 = *(const float4*)(wH + k);
            #pragma unroll
            for (int m = 0; m < MB; ++m) {
                aI[m] += dot4(wi4, *(const float4*)(xS + m * SROW + k));
                aH[m] += dot4(wh4, *(const float4*)(hS + m * SROW + k));
            }
        }
        #pragma unroll
        for (int m = 0; m < MB; ++m) { gI[m * 768 + i] = aI[m]; gH[m * 768 + i] = aH[m]; }
    }
}

__global__ __launch_bounds__(NTHR) void decoder_kernel(
    const int* __restrict__ y,
    const float* __restrict__ enc,
    const float* __restrict__ eh,
    const float* __restrict__ Wih0,
    const float* __restrict__ Whh0,
    const float* __restrict__ bih0,
    const float* __restrict__ bhh0,
    const float* __restrict__ Wih1,
    const float* __restrict__ Whh1,
    const float* __restrict__ bih1,
    const float* __restrict__ bhh1,
    const float* __restrict__ wcW,
    const float* __restrict__ wcb,
    const float* __restrict__ wsW,
    const float* __restrict__ wsb,
    float* __restrict__ out)
{
    __shared__ SMem sm;
    const int tid = threadIdx.x;
    const int b0 = blockIdx.x * MB;

    // init: ht=0, c0=eh[0], c1=eh[1]
    for (int idx = tid; idx < MB * SROW; idx += NTHR) sm.htF[idx] = 0.f;
    for (int idx = tid; idx < MB * HH; idx += NTHR) {
        const int m = idx >> 8, k = idx & 255;
        sm.c0F[m * SROW + k] = eh[(b0 + m) * HH + k];
        sm.c1F[m * SROW + k] = eh[(size_t)BATCH * HH + (b0 + m) * HH + k];
    }
    __syncthreads();

    for (int t = 0; t < TOUT; ++t) {
        if (tid < MB) sm.ymS[tid] = y[(b0 + tid) * TTOT + t];
        __syncthreads();

        // ---- GRU0 GEMV: x = ht(prev), h = c0
        gru_gemv<true>(Wih0, 352, 96, Whh0, bih0, bhh0, sm.htF, sm.c0F, sm.ymS,
                       sm.gI, sm.gH, tid);
        __syncthreads();
        // ---- GRU0 update (elementwise)
        for (int p = tid; p < MB * 256; p += NTHR) {
            const int m = p >> 8, c = p & 255;
            const float r = 1.f / (1.f + __expf(-(sm.gI[m * 768 + c] + sm.gH[m * 768 + c])));
            const float z = 1.f / (1.f + __expf(-(sm.gI[m * 768 + 256 + c] + sm.gH[m * 768 + 256 + c])));
            const float n = tanhf(sm.gI[m * 768 + 512 + c] + r * sm.gH[m * 768 + 512 + c]);
            sm.c0F[m * SROW + c] = (1.f - z) * n + z * sm.c0F[m * SROW + c];
        }
        __syncthreads();

        // ---- GRU1 GEMV: x = c0(new), h = c1
        gru_gemv<false>(Wih1, 256, 0, Whh1, bih1, bhh1, sm.c0F, sm.c1F, sm.ymS,
                        sm.gI, sm.gH, tid);
        __syncthreads();
        // ---- GRU1 update
        for (int p = tid; p < MB * 256; p += NTHR) {
            const int m = p >> 8, c = p & 255;
            const float r = 1.f / (1.f + __expf(-(sm.gI[m * 768 + c] + sm.gH[m * 768 + c])));
            const float z = 1.f / (1.f + __expf(-(sm.gI[m * 768 + 256 + c] + sm.gH[m * 768 + 256 + c])));
            const float n = tanhf(sm.gI[m * 768 + 512 + c] + r * sm.gH[m * 768 + 512 + c]);
            sm.c1F[m * SROW + c] = (1.f - z) * n + z * sm.c1F[m * SROW + c];
        }
        __syncthreads();   // c1 (= out) ready

        // ---- attention pass E: energies[m][s] = enc[m][s][:] . out[m][:]
        #pragma unroll
        for (int pi = 0; pi < 2; ++pi) {
            const int pair = pi * NTHR + tid;
            const int m = pair >> 7, s = pair & 127;
            const float* er = enc + (size_t)((b0 + m) * SS + s) * HH;
            const float* of = sm.c1F + m * SROW;
            float acc = 0.f;
            #pragma unroll 8
            for (int k = 0; k < 256; k += 4)
                acc += dot4(*(const float4*)(er + k), *(const float4*)(of + k));
            sm.eS[m * 132 + s] = acc;
        }
        __syncthreads();

        // ---- softmax over s (per m)
        if (tid < 128) {
            const int m = tid >> 4, j = tid & 15;
            float mx = -3.0e38f;
            #pragma unroll
            for (int q = 0; q < 8; ++q) mx = fmaxf(mx, sm.eS[m * 132 + j * 8 + q]);
            sm.red[tid] = mx;
        }
        __syncthreads();
        if (tid < MB) {
            float mx = -3.0e38f;
            #pragma unroll
            for (int j = 0; j < 16; ++j) mx = fmaxf(mx, sm.red[tid * 16 + j]);
            sm.rowM[tid] = mx;
        }
        __syncthreads();
        #pragma unroll
        for (int pi = 0; pi < 2; ++pi) {
            const int pair = pi * NTHR + tid;
            const int m = pair >> 7, s = pair & 127;
            sm.eS[m * 132 + s] = __expf(sm.eS[m * 132 + s] - sm.rowM[m]);
        }
        __syncthreads();
        if (tid < 128) {
            const int m = tid >> 4, j = tid & 15;
            float sum = 0.f;
            #pragma unroll
            for (int q = 0; q < 8; ++q) sum += sm.eS[m * 132 + j * 8 + q];
            sm.red[tid] = sum;
        }
        __syncthreads();
        if (tid < MB) {
            float sum = 0.f;
            #pragma unroll
            for (int j = 0; j < 16; ++j) sum += sm.red[tid * 16 + j];
            sm.rowS[tid] = 1.f / sum;
        }
        __syncthreads();

        // ---- pass C: ctx[m][h] = (1/sum) * sum_s p[m][s] * enc[m][s][h]  (coalesced)
        {
            const int m = tid >> 6, hc = tid & 63;      // 4 floats per thread
            const float* eb = enc + (size_t)(b0 + m) * SS * HH + hc * 4;
            float4 a = (float4){0.f, 0.f, 0.f, 0.f};
            #pragma unroll 4
            for (int s = 0; s < SS; ++s) {
                const float p = sm.eS[m * 132 + s];
                const float4 u = *(const float4*)(eb + (size_t)s * HH);
                a.x += p * u.x; a.y += p * u.y; a.z += p * u.z; a.w += p * u.w;
            }
            const float inv = sm.rowS[m];
            a.x *= inv; a.y *= inv; a.z *= inv; a.w *= inv;
            *(float4*)(sm.cxF + m * SROW + hc * 4) = a;
        }
        __syncthreads();   // ctx ready

        // ---- wc phase A: partials. thread (i=tid>>1, kh=tid&1):
        //   kh=0: out . wcW[i][0:256] -> gI[m*256+i];  kh=1: ctx . wcW[i][256:512] -> gH[m*256+i]
        {
            const int i = tid >> 1, kh = tid & 1;
            const float* w = wcW + (size_t)i * 512 + kh * 256;
            const float* st = kh ? sm.cxF : sm.c1F;
            float acc[MB];
            #pragma unroll
            for (int m = 0; m < MB; ++m) acc[m] = 0.f;
            #pragma unroll 4
            for (int k = 0; k < 256; k += 4) {
                const float4 w4 = *(const float4*)(w + k);
                #pragma unroll
                for (int m = 0; m < MB; ++m)
                    acc[m] += dot4(w4, *(const float4*)(st + m * SROW + k));
            }
            float* dst = kh ? sm.gH : sm.gI;
            #pragma unroll
            for (int m = 0; m < MB; ++m) dst[m * 256 + i] = acc[m];
        }
        __syncthreads();
        // ---- wc phase B: ht = tanh(p0 + p1 + b)
        for (int p = tid; p < MB * 256; p += NTHR) {
            const int m = p >> 8, i = p & 255;
            sm.htF[m * SROW + i] = tanhf(sm.gI[m * 256 + i] + sm.gH[m * 256 + i] + wcb[i]);
        }
        __syncthreads();   // ht ready

        // ---- ws: logits[m][v] = ht[m] . wsW[v] + wsb[v]
        for (int p = tid; p < MB * VV; p += NTHR) {
            const int m = p / VV, v = p - m * VV;
            const float* w = wsW + (size_t)v * 256;
            const float* h = sm.htF + m * SROW;
            float acc = wsb[v];
            #pragma unroll 8
            for (int k = 0; k < 256; k += 4)
                acc += dot4(*(const float4*)(w + k), *(const float4*)(h + k));
            out[(size_t)((b0 + m) * TOUT + t) * VV + v] = acc;
        }
        __syncthreads();
    }
}

extern "C" void kernel_launch(void* const* d_in, const int* in_sizes, int n_in,
                              void* d_out, int out_size, void* d_ws, size_t ws_size,
                              hipStream_t stream) {
    (void)in_sizes; (void)n_in; (void)out_size; (void)d_ws; (void)ws_size;
    const int* y = (const int*)d_in[0];
    const float* enc  = (const float*)d_in[1];
    const float* eh   = (const float*)d_in[2];
    // d_in[3] = is_training (always 1, teacher forcing)
    const float* Wih0 = (const float*)d_in[4];
    const float* Whh0 = (const float*)d_in[5];
    const float* bih0 = (const float*)d_in[6];
    const float* bhh0 = (const float*)d_in[7];
    const float* Wih1 = (const float*)d_in[8];
    const float* Whh1 = (const float*)d_in[9];
    const float* bih1 = (const float*)d_in[10];
    const float* bhh1 = (const float*)d_in[11];
    const float* wcW  = (const float*)d_in[12];
    const float* wcb  = (const float*)d_in[13];
    const float* wsW  = (const float*)d_in[14];
    const float* wsb  = (const float*)d_in[15];
    float* outp = (float*)d_out;

    decoder_kernel<<<dim3(NBLK), dim3(NTHR), 0, stream>>>(
        y, enc, eh, Wih0, Whh0, bih0, bhh0, Wih1, Whh1, bih1, bhh1,
        wcW, wcb, wsW, wsb, outp);
}